// Round 8
// baseline (797650.098 us; speedup 1.0000x reference)
//
#include <hip/hip_runtime.h>
#include <math.h>

// Problem constants (from reference)
#define VOCABN 8192
#define EMBN   80
#define UNITSN 2048
#define BATCHN 64
#define SEQN   64

typedef _Float16 f16;
typedef _Float16 f16x8 __attribute__((ext_vector_type(8)));
typedef float    f32x4 __attribute__((ext_vector_type(4)));

// final_gemm LDS geometry (proven)
#define BROW 4352

// hbuf layout: [p(2)][g(8)][kt(64)][slot(32)][16B]  -- 512 B per (g,kt) tile
//   byte(p,g,kt) = ((p*8+g)<<15) + (kt<<9); slot s = kq*8 + row; frag at s*16.
//   Tile (g,kt): h rows 8g..8g+7, cols kt*32..kt*32+31, fragment = 8 cols.
#define HBUF_BYTES   (2 * 8 * 64 * 512)
#define FLAGS_OFF    HBUF_BYTES                  // 8 groups x 32 step flags
#define XSLOT_OFF    (FLAGS_OFF + 256 * 4)       // 256 xcc publish slots
#define OUTPRE_OFF   (XSLOT_OFF + 256 * 4)
#define WS_ZERO_B    (OUTPRE_OFF + BATCHN * 4)

// recur K split: 2176 = 4 waves x 544 = 4 x 17 tiles of 32
#define KPW 544

__device__ __forceinline__ f32x4 mfma16(f16x8 a, f16x8 b, f32x4 c) {
    return __builtin_amdgcn_mfma_f32_16x16x32_f16(a, b, c, 0, 0, 0);
}

// ---- coherence primitives -------------------------------------------------
// MALL (sc0 sc1): device-wide coherent, ~900cy. L2 (sc0): XCD-local coherent,
// ~200cy, cached. FAST path uses L2 ops, legal only when the whole group is
// verified to live on one XCD (runtime check below). SAFE path = MALL.
__device__ __forceinline__ int bypass_load_b32(const void* p) {
    int r;
    asm volatile("global_load_dword %0, %1, off sc0 sc1\n\ts_waitcnt vmcnt(0)"
                 : "=v"(r) : "v"(p) : "memory");
    return r;
}
__device__ __forceinline__ void bypass_store_b32(void* p, unsigned int v) {
    asm volatile("global_store_dword %0, %1, off sc0 sc1"
                 :: "v"(p), "v"(v) : "memory");
}
template<bool MALL>
__device__ __forceinline__ void h_load16(f16x8* dst, const void* p) {
    if constexpr (MALL)
        asm volatile("global_load_dwordx4 %0, %1, off sc0 sc1"
                     : "=v"(*dst) : "v"(p) : "memory");
    else
        asm volatile("global_load_dwordx4 %0, %1, off sc0"
                     : "=v"(*dst) : "v"(p) : "memory");
}
template<bool MALL>
__device__ __forceinline__ int flag_load(const void* p) {
    int r;
    if constexpr (MALL)
        asm volatile("global_load_dword %0, %1, off sc0 sc1\n\ts_waitcnt vmcnt(0)"
                     : "=v"(r) : "v"(p) : "memory");
    else
        asm volatile("global_load_dword %0, %1, off sc0\n\ts_waitcnt vmcnt(0)"
                     : "=v"(r) : "v"(p) : "memory");
    return r;
}
template<bool MALL>
__device__ __forceinline__ void st_b32(void* p, unsigned int v) {
    if constexpr (MALL)
        asm volatile("global_store_dword %0, %1, off sc0 sc1"
                     :: "v"(p), "v"(v) : "memory");
    else
        asm volatile("global_store_dword %0, %1, off sc0"
                     :: "v"(p), "v"(v) : "memory");
}
__device__ __forceinline__ void wait_vm0(void) {
    asm volatile("s_waitcnt vmcnt(0)" ::: "memory");
    __builtin_amdgcn_sched_barrier(0);
}
__device__ __forceinline__ unsigned int us(f16 h) {
    return (unsigned int)__builtin_bit_cast(unsigned short, h);
}

// ---------------------------------------------------------------------------
// The step loop, templated on coherence scope. Geometry: this WG = row-group
// g (batch rows 8g..8g+7) x col-chunk [c0, c0+64). Weights register-resident.
// ---------------------------------------------------------------------------
template<bool MALL>
__device__ __forceinline__ void run_steps(
    f16x8 (&b)[17][4], char* __restrict__ hb, int* __restrict__ gflags,
    const float* __restrict__ emb, float* __restrict__ red,
    f16 (*__restrict__ xlds)[8][96], const int (*__restrict__ idxlds)[SEQN],
    const float* __restrict__ bias, int g, int c0, int chunk, int tid)
{
    const int lane = tid & 63, wv = tid >> 6, l16 = lane & 15, lq = lane >> 4;
    // producer mapping: thread -> (row prow 0..7, 2 cols at c0+pcb)
    const int prow = tid >> 5;
    const int pcb  = (tid & 31) * 2;
    const float bs0 = bias[c0 + pcb], bs1 = bias[c0 + pcb + 1];
    const int gc    = c0 + pcb;
    const int kt_p  = gc >> 5;
    const int cc    = gc & 31;
    const int ps    = (cc >> 3) * 8 + prow;
    const int pbyte = ps * 16 + (cc & 7) * 2;
    const int asl   = lq * 8 + (l16 & 7);   // consumer A-fragment slot (rows 8-15 dup)
    // reduce mapping
    const int tl  = pcb >> 4;
    const int la0 = ((prow >> 2) << 4) | (pcb & 15);
    const int rg  = prow & 3;

    for (int t = 0; t < SEQN; ++t) {
        const int p = t & 1;

        f32x4 acc[4];
#pragma unroll
        for (int ct = 0; ct < 4; ++ct) acc[ct] = (f32x4){0.f, 0.f, 0.f, 0.f};
        {
            const char* hsrc = hb + ((p * 8 + g) << 15) + (asl << 4);
            f16x8 av[17];
#pragma unroll
            for (int i = 0; i < 17; ++i) {
                if (wv * KPW + i * 32 < UNITSN)   // wave-uniform
                    h_load16<MALL>(&av[i], hsrc + ((wv * 17 + i) << 9));
            }
            f16x8 axf0 = {}, axf1 = {}, axf2 = {};
            if (wv == 3) {   // x-part k = 2048..2143
                axf0 = *(const f16x8*)(&xlds[p][l16 & 7][0  + lq * 8]);
                axf1 = *(const f16x8*)(&xlds[p][l16 & 7][32 + lq * 8]);
                axf2 = *(const f16x8*)(&xlds[p][l16 & 7][64 + lq * 8]);
            }
            wait_vm0();
#pragma unroll
            for (int i = 0; i < 17; ++i) {
                if (wv * KPW + i * 32 < UNITSN) {
#pragma unroll
                    for (int ct = 0; ct < 4; ++ct)
                        acc[ct] = mfma16(av[i], b[i][ct], acc[ct]);
                }
            }
            if (wv == 3) {
#pragma unroll
                for (int ct = 0; ct < 4; ++ct) acc[ct] = mfma16(axf0, b[13][ct], acc[ct]);
#pragma unroll
                for (int ct = 0; ct < 4; ++ct) acc[ct] = mfma16(axf1, b[14][ct], acc[ct]);
#pragma unroll
                for (int ct = 0; ct < 4; ++ct) acc[ct] = mfma16(axf2, b[15][ct], acc[ct]);
            }
        }
#pragma unroll
        for (int ct = 0; ct < 4; ++ct)
            *(f32x4*)(&red[(((wv * 4) + ct) * 64 + lane) * 4]) = acc[ct];
        __syncthreads();

        // reduce 4 waves, bias, tanh, pack 2 f16, one 4B scope-store
        {
            float s0 = bs0, s1 = bs1;
#pragma unroll
            for (int w = 0; w < 4; ++w) {
                s0 += red[(((w * 4) + tl) * 64 + la0) * 4 + rg];
                s1 += red[(((w * 4) + tl) * 64 + la0 + 1) * 4 + rg];
            }
            const float v0 = tanhf(s0), v1 = tanhf(s1);
            const unsigned int pk = us((f16)v0) | (us((f16)v1) << 16);
            char* dst = hb + ((((t + 1) & 1) * 8 + g) << 15) + (kt_p << 9) + pbyte;
            st_b32<MALL>(dst, pk);
        }
        // drain: h store acked at coherence point before anyone passes barrier
        asm volatile("s_waitcnt vmcnt(0)" ::: "memory");
        __syncthreads();

        if (t == SEQN - 1) break;   // final h in parity 0

        // publish: own slot, monotonic (flags zeroed each launch)
        if (tid == 0)
            st_b32<MALL>(&gflags[chunk], (unsigned int)(t + 1));

        // overlap: stage x_{t+1} while flags converge
        {
            const int r  = tid >> 5;
            const int kb = (tid & 31) * 3;
            const float* erow = emb + (size_t)idxlds[r][t + 1] * EMBN;
            const int buf = (t + 1) & 1;
#pragma unroll
            for (int q = 0; q < 3; ++q) {
                const int k = kb + q;
                xlds[buf][r][k] = (f16)((k < EMBN) ? erow[k] : 0.f);
            }
        }

        // wave-0 poll of the group's 32 flags (one line)
        if (wv == 0) {
            int tries = 0;
            for (;;) {
                const int v = flag_load<MALL>(&gflags[lane & 31]);
                if (__all(v > t)) break;
                __builtin_amdgcn_s_sleep(1);
                if (++tries > 150000) break;   // safety valve
            }
        }
        __syncthreads();   // releases waves 1..3; xlds[t+1] ready
    }
}

// ---------------------------------------------------------------------------
// Recurrent kernel v7: 256 WGs = 8 row-groups (8 rows, group = blockIdx%8 so
// a group maps to one XCD under round-robin dispatch) x 32 col-chunks (64
// cols). Runtime XCD-uniformity check selects L2-coherent FAST path or
// MALL-coherent SAFE path (correct under any placement).
// ---------------------------------------------------------------------------
__global__ __launch_bounds__(256, 1)
void rnn_recur(const int* __restrict__ inputs, const float* __restrict__ emb,
               const float* __restrict__ Wx, const float* __restrict__ Wh,
               const float* __restrict__ bias, f16* __restrict__ hbuf,
               int* __restrict__ flags)
{
    // union: prologue weight staging Wtmp [768][65] f16; then red [4][4][64][4] f32
    __shared__ __align__(16) char smem[99840];
    __shared__ f16  xlds[2][8][96];
    __shared__ int  idxlds[8][SEQN];
    __shared__ int  s_fast;

    const int tid = threadIdx.x;
    const int wg  = blockIdx.x;
    const int g     = wg & 7;           // row group == XCD slot under %8 heuristic
    const int chunk = wg >> 3;          // col chunk 0..31
    const int c0  = chunk * 64;

    // publish my XCD id early (always MALL; placement-agnostic)
    unsigned int xcc;
    asm volatile("s_getreg_b32 %0, hwreg(HW_REG_XCC_ID)" : "=s"(xcc));
    xcc &= 0xff;
    int* xslots = flags + 256;
    if (tid == 0) bypass_store_b32(&xslots[wg], xcc | 0x100);

    for (int i = tid; i < 8 * SEQN; i += 256)
        idxlds[i >> 6][i & 63] = inputs[(g * 8 + (i >> 6)) * SEQN + (i & 63)];

    const int lane = tid & 63;
    const int wv   = tid >> 6;
    const int l16  = lane & 15;
    const int lq   = lane >> 4;

    // ---- prologue: Wh/Wx cols [c0,c0+64) -> registers via LDS staging ----
    f16x8 b[17][4];
    {
        f16* Wtmp = (f16*)smem;     // [768][65]
        for (int ch = 0; ch < 3; ++ch) {
            const int base  = ch * 768;
            const int nrows = (base + 768 <= 2176) ? 768 : (2176 - base);
            for (int rp = 0; rp < nrows; rp += 16) {
                const int r_ = rp + (tid >> 4);
                if (r_ < nrows) {
                    const int k = base + r_;
                    float4 w = {0.f, 0.f, 0.f, 0.f};
                    if (k < UNITSN)
                        w = *(const float4*)(Wh + (size_t)k * UNITSN + c0 + (tid & 15) * 4);
                    else if (k - UNITSN < EMBN)
                        w = *(const float4*)(Wx + (size_t)(k - UNITSN) * UNITSN + c0 + (tid & 15) * 4);
                    f16* d = &Wtmp[r_ * 65 + (tid & 15) * 4];
                    d[0] = (f16)w.x; d[1] = (f16)w.y; d[2] = (f16)w.z; d[3] = (f16)w.w;
                }
            }
            __syncthreads();
#pragma unroll
            for (int i = 0; i < 17; ++i) {
                const int k = wv * KPW + i * 32;          // wave-uniform
                if (k >= base && k < base + 768) {
                    const int kl = k - base + lq * 8;
#pragma unroll
                    for (int ct = 0; ct < 4; ++ct) {
#pragma unroll
                        for (int e = 0; e < 8; ++e)
                            b[i][ct][e] = Wtmp[(kl + e) * 65 + ct * 16 + l16];
                    }
                }
            }
            __syncthreads();
        }
    }

    // stage x_0
    {
        const int r  = tid >> 5;
        const int kb = (tid & 31) * 3;
        const float* erow = emb + (size_t)idxlds[r][0] * EMBN;
#pragma unroll
        for (int q = 0; q < 3; ++q) {
            const int k = kb + q;
            xlds[0][r][k] = (f16)((k < EMBN) ? erow[k] : 0.f);
        }
    }

    // XCD-uniformity check (by now all 256 co-resident WGs have published)
    if (tid < 64) {
        int v = 0, tries = 0;
        for (;;) {
            v = bypass_load_b32(&xslots[g + (lane & 31) * 8]);
            if (__all((v & 0x100) != 0)) break;
            __builtin_amdgcn_s_sleep(2);
            if (++tries > 2000000) break;   // safety -> SAFE path
        }
        const int ok = (tries <= 2000000) && __all((v & 0xff) == (int)xcc);
        if (tid == 0) s_fast = ok ? 1 : 0;
    }
    __syncthreads();

    float* red = (float*)smem;
    int* gflags = flags + g * 32;
    if (s_fast)
        run_steps<false>(b, (char*)hbuf, gflags, emb, red, xlds, idxlds, bias, g, c0, chunk, tid);
    else
        run_steps<true>(b, (char*)hbuf, gflags, emb, red, xlds, idxlds, bias, g, c0, chunk, tid);
}

// ---------------------------------------------------------------------------
// load_wslice for final_gemm (proven): cols [c0,c0+32) of W + Wxp into
// swizzled LDS: byte = uu*BROW + ((2k)^((uu&15)<<4)).
// ---------------------------------------------------------------------------
__device__ __forceinline__ void load_wslice(const float* __restrict__ W,
                                            const float* __restrict__ Wxp,
                                            int c0, int tid, unsigned char* Blds)
{
    const int j0 = tid >> 3, l8 = tid & 7;
    for (int it = 0; it < 64; ++it) {
        const int j = j0 + it * 32;
        const float4 w = *(const float4*)(W + (size_t)j * UNITSN + c0 + l8 * 4);
        const float vals[4] = {w.x, w.y, w.z, w.w};
#pragma unroll
        for (int q = 0; q < 4; ++q) {
            const int uu = l8 * 4 + q;
            *(f16*)(Blds + uu * BROW + ((2 * j) ^ ((uu & 15) << 4))) = (f16)vals[q];
        }
    }
    for (int j2 = j0; j2 < 96; j2 += 32) {
        float vals[4] = {0.f, 0.f, 0.f, 0.f};
        if (j2 < EMBN) {
            const float4 w = *(const float4*)(Wxp + (size_t)j2 * UNITSN + c0 + l8 * 4);
            vals[0] = w.x; vals[1] = w.y; vals[2] = w.z; vals[3] = w.w;
        }
#pragma unroll
        for (int q = 0; q < 4; ++q) {
            const int uu = l8 * 4 + q;
            const int k = 2048 + j2;
            *(f16*)(Blds + uu * BROW + ((2 * k) ^ ((uu & 15) << 4))) = (f16)vals[q];
        }
    }
}

// ---------------------------------------------------------------------------
// Final layer-5 at t=63 via MFMA (structure proven; h addressing updated to
// the 8-group tiled hbuf; plain cached loads — dispatch-boundary coherence).
// ---------------------------------------------------------------------------
__global__ __launch_bounds__(256)
void final_gemm(const int* __restrict__ inputs, const float* __restrict__ emb,
                const float* __restrict__ Wx, const float* __restrict__ Wh,
                const float* __restrict__ bias, const float* __restrict__ Wout,
                const f16* __restrict__ hbuf, float* __restrict__ out_pre)
{
    __shared__ unsigned char Blds[32 * BROW];   // 139264 B
    __shared__ f16  xlds[64][96];               // 12288 B
    __shared__ float red[4][64][4];             // 4096 B
    __shared__ float rowacc[64][4];             // 1024 B

    const int tid = threadIdx.x;
    const int c0  = blockIdx.x * 32;
    const float* Wh5 = Wh + (size_t)5 * UNITSN * UNITSN;
    const float* Wx5 = Wx + (size_t)5 * EMBN * UNITSN;
    const float* b5  = bias + 5 * UNITSN;
    const char* hb = (const char*)hbuf;

    load_wslice(Wh5, Wx5, c0, tid, Blds);
    {
        const int r  = tid >> 2;
        const int kb = (tid & 3) * 24;
        const float* erow = emb + (size_t)inputs[r * SEQN + SEQN - 1] * EMBN;
#pragma unroll
        for (int q = 0; q < 24; ++q) {
            const int k = kb + q;
            xlds[r][k] = (f16)((k < EMBN) ? erow[k] : 0.f);
        }
    }
    rowacc[tid >> 2][tid & 3] = 0.f;
    __syncthreads();

    const int lane = tid & 63;
    const int wv   = tid >> 6;
    const int l16  = lane & 15;
    const int lq   = lane >> 4;

    for (int ct = 0; ct < 2; ++ct) {
        f32x4 acc[4];
#pragma unroll
        for (int rt = 0; rt < 4; ++rt) acc[rt] = (f32x4){0.f, 0.f, 0.f, 0.f};
        const unsigned char* brow = Blds + (ct * 16 + l16) * BROW;
        const int swz = l16 << 4;
#pragma unroll
        for (int rt = 0; rt < 4; ++rt) {   // rows 16rt..16rt+15 = groups 2rt,2rt+1
            const int gg = rt * 2 + (l16 >> 3);
            const int s  = lq * 8 + (l16 & 7);
            const char* hsrc = hb + (gg << 15) + (s << 4);   // parity 0
            f16x8 av[16];
#pragma unroll
            for (int kk = 0; kk < 16; ++kk)
                av[kk] = *(const f16x8*)(hsrc + ((wv * 16 + kk) << 9));
            f16x8 ax;
            if (wv < 3) ax = *(const f16x8*)(&xlds[rt * 16 + l16][wv * 32 + lq * 8]);
#pragma unroll
            for (int kk = 0; kk < 16; ++kk) {
                const int k0 = wv * 512 + kk * 32 + lq * 8;
                acc[rt] = mfma16(av[kk], *(const f16x8*)(brow + ((2 * k0) ^ swz)), acc[rt]);
            }
            if (wv < 3) {
                const int k0 = 2048 + wv * 32 + lq * 8;
                acc[rt] = mfma16(ax, *(const f16x8*)(brow + ((2 * k0) ^ swz)), acc[rt]);
            }
        }
        if (wv == 0) {
#pragma unroll
            for (int rt = 0; rt < 4; ++rt) *(f32x4*)(&red[rt][lane][0]) = acc[rt];
        }
        __syncthreads();
#pragma unroll
        for (int w = 1; w < 4; ++w) {
            if (wv == w) {
#pragma unroll
                for (int rt = 0; rt < 4; ++rt) {
                    f32x4 cur = *(f32x4*)(&red[rt][lane][0]);
                    cur += acc[rt];
                    *(f32x4*)(&red[rt][lane][0]) = cur;
                }
            }
            __syncthreads();
        }
        {
            const int r = tid >> 2;
            float rsum = 0.f;
#pragma unroll
            for (int q = 0; q < 4; ++q) {
                const int cl = (tid & 3) * 4 + q;
                const int c  = ct * 16 + cl;
                const int lidx = (((r & 15) >> 2) << 4) + cl;
                float v = red[r >> 4][lidx][r & 3] + b5[c0 + c];
                v = tanhf(v);
                rsum += v * Wout[c0 + c];
            }
            rowacc[r][tid & 3] += rsum;
        }
        __syncthreads();
    }
    if (tid < 64) {
        const float s = rowacc[tid][0] + rowacc[tid][1] + rowacc[tid][2] + rowacc[tid][3];
        atomicAdd(&out_pre[tid], s);
    }
}

__global__ void final_out(const float* __restrict__ out_pre,
                          const float* __restrict__ bout, float* __restrict__ out)
{
    const int b = threadIdx.x;
    if (b < BATCHN) out[b] = 1.f / (1.f + expf(-(out_pre[b] + bout[0])));
}

// ---------------------------------------------------------------------------
extern "C" void kernel_launch(void* const* d_in, const int* in_sizes, int n_in,
                              void* d_out, int out_size, void* d_ws, size_t ws_size,
                              hipStream_t stream) {
    (void)in_sizes; (void)n_in; (void)out_size; (void)ws_size;
    const int*   inputs = (const int*)d_in[0];
    const float* emb    = (const float*)d_in[1];
    const float* Wx     = (const float*)d_in[2];
    const float* Wh     = (const float*)d_in[3];
    const float* bias   = (const float*)d_in[4];
    const float* Wout   = (const float*)d_in[5];
    const float* bout   = (const float*)d_in[6];
    float* out = (float*)d_out;

    f16*   hbuf    = (f16*)d_ws;
    int*   flags   = (int*)((char*)d_ws + FLAGS_OFF);
    float* out_pre = (float*)((char*)d_ws + OUTPRE_OFF);

    // reset h state, step flags, xcc slots, output accumulators
    (void)hipMemsetAsync(d_ws, 0, WS_ZERO_B, stream);

    hipStreamCaptureStatus cs = hipStreamCaptureStatusNone;
    (void)hipStreamIsCapturing(stream, &cs);
    if (cs == hipStreamCaptureStatusActive) {
        rnn_recur<<<dim3(256), dim3(256), 0, stream>>>(inputs, emb, Wx, Wh, bias, hbuf, flags);
    } else {
        void* args[] = {(void*)&inputs, (void*)&emb, (void*)&Wx, (void*)&Wh,
                        (void*)&bias, (void*)&hbuf, (void*)&flags};
        hipError_t e = hipLaunchCooperativeKernel((const void*)rnn_recur, dim3(256), dim3(256),
                                                  args, 0, stream);
        if (e != hipSuccess) {
            rnn_recur<<<dim3(256), dim3(256), 0, stream>>>(inputs, emb, Wx, Wh, bias, hbuf, flags);
        }
    }
    final_gemm<<<dim3(64), dim3(256), 0, stream>>>(inputs, emb, Wx, Wh, bias, Wout, hbuf, out_pre);
    final_out<<<dim3(1), dim3(64), 0, stream>>>(out_pre, bout, out);
}

// Round 9
// 427.733 us; speedup vs baseline: 1864.8303x; 1864.8303x over previous
//
#include <hip/hip_runtime.h>
#include <math.h>

// Problem constants (from reference)
#define VOCABN 8192
#define EMBN   80
#define UNITSN 2048
#define BATCHN 64
#define SEQN   64

typedef _Float16 f16;
typedef _Float16 f16x8 __attribute__((ext_vector_type(8)));
typedef float    f32x4 __attribute__((ext_vector_type(4)));
typedef unsigned int u32x2 __attribute__((ext_vector_type(2)));
typedef unsigned int u32x4 __attribute__((ext_vector_type(4)));

// final_gemm LDS geometry (proven)
#define BROW 4352

// hbuf layout (tiled to MFMA fragment order):
//   hbuf[p(2)][g(4)][kt(64)][lane(64)][8 f16]  -- 1 KB per (g,kt) tile
//   byte(p,g,kt) = ((p*4+g)<<16) + (kt<<10); lane fragment at +lane*16.
// Every stored f16 carries the step EPOCH in its LSB: epoch(t) = (t>>1)&1 for
// the h_t buffer. Consumers poll their own fragments until all LSBs match —
// the data is its own ready flag (no flags, no store drain, no release hop).
#define HBUF_BYTES   (2 * 4 * 64 * 1024)
#define PAR_BYTES    (4 * 64 * 1024)
#define FLAGS_OFF    HBUF_BYTES                 // legacy/unused, kept zeroed
#define OUTPRE_OFF   (FLAGS_OFF + 256 * 4)
#define WS_ZERO_B    (OUTPRE_OFF + BATCHN * 4)

// recur K split: 2176 = 4 waves x 544 = 4 x 17 tiles of 32
#define KPW 544

__device__ __forceinline__ f32x4 mfma16(f16x8 a, f16x8 b, f32x4 c) {
    return __builtin_amdgcn_mfma_f32_16x16x32_f16(a, b, c, 0, 0, 0);
}

// MALL-coherent (bypass L1+L2) primitives — the ONLY way hbuf is accessed in
// the recurrent loop. sc0 sc1 proven correct (rounds 4-7); sc0-only proven
// broken for polling (round 8).
__device__ __forceinline__ void bypass_load_b16(f16x8* dst, const void* p) {
    asm volatile("global_load_dwordx4 %0, %1, off sc0 sc1"
                 : "=v"(*dst) : "v"(p) : "memory");
}
__device__ __forceinline__ void bypass_store_b64(void* p, u32x2 v) {
    asm volatile("global_store_dwordx2 %0, %1, off sc0 sc1"
                 :: "v"(p), "v"(v) : "memory");
}
__device__ __forceinline__ void wait_vm0(void) {
    asm volatile("s_waitcnt vmcnt(0)" ::: "memory");
    __builtin_amdgcn_sched_barrier(0);
}
__device__ __forceinline__ unsigned int us(f16 h) {
    return (unsigned int)__builtin_bit_cast(unsigned short, h);
}

// ---------------------------------------------------------------------------
// Recurrent kernel v9: 128 WGs = 4 row-groups (16 rows) x 32 col-chunks (64
// cols); register-resident weights (proven round 7). Sync v9: flag-free
// epoch-LSB dataflow — consumers poll their own h fragments until every f16
// LSB equals the expected epoch bit, re-loading only unready tiles.
// ---------------------------------------------------------------------------
__global__ __launch_bounds__(256, 1)
void rnn_recur(const int* __restrict__ inputs, const float* __restrict__ emb,
               const float* __restrict__ Wx, const float* __restrict__ Wh,
               const float* __restrict__ bias, f16* __restrict__ hbuf,
               int* __restrict__ flags)
{
    (void)flags;
    // union: prologue weight staging Wtmp [768][65] f16; then red [4][4][64][4] f32
    __shared__ __align__(16) char smem[99840];
    __shared__ f16  xlds[2][16][96];            // double-buffered x_t
    __shared__ int  idxlds[16][SEQN];           // token ids

    const int tid = threadIdx.x;
    const int wg  = blockIdx.x;
    const int g     = wg >> 5;          // row group 0..3 (rows 16g..16g+15)
    const int wslot = wg & 31;          // col-chunk 0..31
    const int c0  = wslot * 64;         // output column base
    const int g16 = g * 16;
    (void)wslot;

    for (int i = tid; i < 16 * SEQN; i += 256)
        idxlds[i >> 6][i & 63] = inputs[(g16 + (i >> 6)) * SEQN + (i & 63)];

    const int lane = tid & 63;
    const int wv   = tid >> 6;      // wave 0..3: K-split
    const int l16  = lane & 15;
    const int lq   = lane >> 4;

    // ---- prologue: Wh/Wx cols [c0,c0+64) -> registers via LDS staging ----
    f16x8 b[17][4];
    {
        f16* Wtmp = (f16*)smem;     // [768][65]
        for (int ch = 0; ch < 3; ++ch) {
            const int base  = ch * 768;
            const int nrows = (base + 768 <= 2176) ? 768 : (2176 - base);
            for (int rp = 0; rp < nrows; rp += 16) {
                const int r_ = rp + (tid >> 4);
                if (r_ < nrows) {
                    const int k = base + r_;
                    float4 w = {0.f, 0.f, 0.f, 0.f};
                    if (k < UNITSN)
                        w = *(const float4*)(Wh + (size_t)k * UNITSN + c0 + (tid & 15) * 4);
                    else if (k - UNITSN < EMBN)
                        w = *(const float4*)(Wx + (size_t)(k - UNITSN) * UNITSN + c0 + (tid & 15) * 4);
                    f16* d = &Wtmp[r_ * 65 + (tid & 15) * 4];
                    d[0] = (f16)w.x; d[1] = (f16)w.y; d[2] = (f16)w.z; d[3] = (f16)w.w;
                }
            }
            __syncthreads();
#pragma unroll
            for (int i = 0; i < 17; ++i) {
                const int k = wv * KPW + i * 32;          // wave-uniform
                if (k >= base && k < base + 768) {
                    const int kl = k - base + lq * 8;
#pragma unroll
                    for (int ct = 0; ct < 4; ++ct) {
#pragma unroll
                        for (int e = 0; e < 8; ++e)
                            b[i][ct][e] = Wtmp[(kl + e) * 65 + ct * 16 + l16];
                    }
                }
            }
            __syncthreads();
        }
    }

    // stage x_0
    {
        const int r  = tid >> 4;
        const int kb = (tid & 15) * 6;
        const float* erow = emb + (size_t)idxlds[r][0] * EMBN;
#pragma unroll
        for (int q = 0; q < 6; ++q) {
            const int k = kb + q;
            xlds[0][r][k] = (f16)((k < EMBN) ? erow[k] : 0.f);
        }
    }
    __syncthreads();

    // reduce-phase mapping: thread -> (row rr, cols cb..cb+3)
    const int rr = tid >> 4;
    const int cb = (tid & 15) * 4;
    float bias4[4];
#pragma unroll
    for (int q = 0; q < 4; ++q) bias4[q] = bias[c0 + cb + q];
    // producer store address (tiled layout)
    const int gc     = c0 + cb;
    const int kt_p   = gc >> 5;
    const int cc     = gc & 31;
    const int lane_t = ((cc >> 3) << 4) | rr;
    const int pbyte  = lane_t * 16 + (cc & 7) * 2;

    char* hb = (char*)hbuf;
    float* red = (float*)smem;   // [4 wv][4 ct][64 lane][4]

    // tiles this wave needs (guard is wave-uniform, compile-time unrolled)
    unsigned all_mask = 0;
#pragma unroll
    for (int i = 0; i < 17; ++i)
        if (wv * KPW + i * 32 < UNITSN) all_mask |= (1u << i);

    for (int t = 0; t < SEQN; ++t) {
        const int p = t & 1;
        const unsigned int eM = ((t >> 1) & 1) ? 0x00010001u : 0u;

        // ---- epoch-LSB poll: load own fragments until all LSBs match ----
        f16x8 av[17];
        const char* hsrc = hb + ((p * 4 + g) << 16) + (lane << 4);
        unsigned rdy = 0;
        int tries = 0;
        for (;;) {
#pragma unroll
            for (int i = 0; i < 17; ++i)
                if ((wv * KPW + i * 32 < UNITSN) && !((rdy >> i) & 1))
                    bypass_load_b16(&av[i], hsrc + ((wv * 17 + i) << 10));
            wait_vm0();
#pragma unroll
            for (int i = 0; i < 17; ++i) {
                if ((wv * KPW + i * 32 < UNITSN) && !((rdy >> i) & 1)) {
                    const u32x4 d = __builtin_bit_cast(u32x4, av[i]);
                    const bool ok = ((d[0] & 0x00010001u) == eM)
                                 && ((d[1] & 0x00010001u) == eM)
                                 && ((d[2] & 0x00010001u) == eM)
                                 && ((d[3] & 0x00010001u) == eM);
                    if (__all(ok)) rdy |= (1u << i);
                }
            }
            if ((rdy & all_mask) == all_mask) break;
            if (++tries > 30000) break;   // safety valve (bug insurance only)
            __builtin_amdgcn_s_sleep(1);
        }

        // ---- MFMA: acc[16x64] = h_prev @ Wh + x_t @ Wx, K split by wave ----
        f32x4 acc[4];
#pragma unroll
        for (int ct = 0; ct < 4; ++ct) acc[ct] = (f32x4){0.f, 0.f, 0.f, 0.f};
        {
            f16x8 axf0 = {}, axf1 = {}, axf2 = {};
            if (wv == 3) {   // x-part k = 2048..2143
                axf0 = *(const f16x8*)(&xlds[p][l16][0 * 32 + lq * 8]);
                axf1 = *(const f16x8*)(&xlds[p][l16][1 * 32 + lq * 8]);
                axf2 = *(const f16x8*)(&xlds[p][l16][2 * 32 + lq * 8]);
            }
#pragma unroll
            for (int i = 0; i < 17; ++i) {
                if (wv * KPW + i * 32 < UNITSN) {
#pragma unroll
                    for (int ct = 0; ct < 4; ++ct)
                        acc[ct] = mfma16(av[i], b[i][ct], acc[ct]);
                }
            }
            if (wv == 3) {
#pragma unroll
                for (int ct = 0; ct < 4; ++ct) acc[ct] = mfma16(axf0, b[13][ct], acc[ct]);
#pragma unroll
                for (int ct = 0; ct < 4; ++ct) acc[ct] = mfma16(axf1, b[14][ct], acc[ct]);
#pragma unroll
                for (int ct = 0; ct < 4; ++ct) acc[ct] = mfma16(axf2, b[15][ct], acc[ct]);
            }
        }
#pragma unroll
        for (int ct = 0; ct < 4; ++ct)
            *(f32x4*)(&red[(((wv * 4) + ct) * 64 + lane) * 4]) = acc[ct];
        __syncthreads();

        // ---- reduce 4 waves, bias, tanh, epoch-LSB pack, 8B bypass store ----
        {
            const unsigned int ebM = (((t + 1) >> 1) & 1) ? 0x00010001u : 0u;
            float vv[4];
#pragma unroll
            for (int q = 0; q < 4; ++q) {
                const int c  = cb + q;
                const int tl = c >> 4;
                const int la = ((rr >> 2) << 4) | (c & 15);
                const int rg = rr & 3;
                float s = bias4[q];
#pragma unroll
                for (int w = 0; w < 4; ++w)
                    s += red[(((w * 4) + tl) * 64 + la) * 4 + rg];
                vv[q] = tanhf(s);
            }
            u32x2 pk;
            pk[0] = ((us((f16)vv[0]) & 0xFFFEu) | ((us((f16)vv[1]) & 0xFFFEu) << 16)) | ebM;
            pk[1] = ((us((f16)vv[2]) & 0xFFFEu) | ((us((f16)vv[3]) & 0xFFFEu) << 16)) | ebM;
            char* dst = hb + ((((t + 1) & 1) * 4 + g) << 16) + (kt_p << 10) + pbyte;
            bypass_store_b64(dst, pk);   // fire-and-forget: LSBs are the flag
        }

        // stage x_{t+1} (cached loads; L1/L2 never invalidated)
        if (t < SEQN - 1) {
            const int r  = tid >> 4;
            const int kb = (tid & 15) * 6;
            const float* erow = emb + (size_t)idxlds[r][t + 1] * EMBN;
            const int buf = (t + 1) & 1;
#pragma unroll
            for (int q = 0; q < 6; ++q) {
                const int k = kb + q;
                xlds[buf][r][k] = (f16)((k < EMBN) ? erow[k] : 0.f);
            }
        }
        __syncthreads();   // red reuse + xlds[t+1] ready
    }
}

// ---------------------------------------------------------------------------
// load_wslice for final_gemm (proven): cols [c0,c0+32) of W + Wxp into
// swizzled LDS: byte = uu*BROW + ((2k)^((uu&15)<<4)).
// ---------------------------------------------------------------------------
__device__ __forceinline__ void load_wslice(const float* __restrict__ W,
                                            const float* __restrict__ Wxp,
                                            int c0, int tid, unsigned char* Blds)
{
    const int j0 = tid >> 3, l8 = tid & 7;
    for (int it = 0; it < 64; ++it) {
        const int j = j0 + it * 32;
        const float4 w = *(const float4*)(W + (size_t)j * UNITSN + c0 + l8 * 4);
        const float vals[4] = {w.x, w.y, w.z, w.w};
#pragma unroll
        for (int q = 0; q < 4; ++q) {
            const int uu = l8 * 4 + q;
            *(f16*)(Blds + uu * BROW + ((2 * j) ^ ((uu & 15) << 4))) = (f16)vals[q];
        }
    }
    for (int j2 = j0; j2 < 96; j2 += 32) {
        float vals[4] = {0.f, 0.f, 0.f, 0.f};
        if (j2 < EMBN) {
            const float4 w = *(const float4*)(Wxp + (size_t)j2 * UNITSN + c0 + l8 * 4);
            vals[0] = w.x; vals[1] = w.y; vals[2] = w.z; vals[3] = w.w;
        }
#pragma unroll
        for (int q = 0; q < 4; ++q) {
            const int uu = l8 * 4 + q;
            const int k = 2048 + j2;
            *(f16*)(Blds + uu * BROW + ((2 * k) ^ ((uu & 15) << 4))) = (f16)vals[q];
        }
    }
}

// ---------------------------------------------------------------------------
// Final layer-5 at t=63 via MFMA (proven round 7; h carries forced LSBs —
// <=1 ulp perturbation, same order as f16 rounding).
// ---------------------------------------------------------------------------
__global__ __launch_bounds__(256)
void final_gemm(const int* __restrict__ inputs, const float* __restrict__ emb,
                const float* __restrict__ Wx, const float* __restrict__ Wh,
                const float* __restrict__ bias, const float* __restrict__ Wout,
                const f16* __restrict__ hbuf, float* __restrict__ out_pre)
{
    __shared__ unsigned char Blds[32 * BROW];   // 139264 B
    __shared__ f16  xlds[64][96];               // 12288 B
    __shared__ float red[4][64][4];             // 4096 B
    __shared__ float rowacc[64][4];             // 1024 B

    const int tid = threadIdx.x;
    const int c0  = blockIdx.x * 32;
    const float* Wh5 = Wh + (size_t)5 * UNITSN * UNITSN;
    const float* Wx5 = Wx + (size_t)5 * EMBN * UNITSN;
    const float* b5  = bias + 5 * UNITSN;
    const char* hb = (const char*)hbuf;

    load_wslice(Wh5, Wx5, c0, tid, Blds);
    {
        const int r  = tid >> 2;
        const int kb = (tid & 3) * 24;
        const float* erow = emb + (size_t)inputs[r * SEQN + SEQN - 1] * EMBN;
#pragma unroll
        for (int q = 0; q < 24; ++q) {
            const int k = kb + q;
            xlds[r][k] = (f16)((k < EMBN) ? erow[k] : 0.f);
        }
    }
    rowacc[tid >> 2][tid & 3] = 0.f;
    __syncthreads();

    const int lane = tid & 63;
    const int wv   = tid >> 6;
    const int l16  = lane & 15;
    const int lq   = lane >> 4;

    for (int ct = 0; ct < 2; ++ct) {
        f32x4 acc[4];
#pragma unroll
        for (int rt = 0; rt < 4; ++rt) acc[rt] = (f32x4){0.f, 0.f, 0.f, 0.f};
        const unsigned char* brow = Blds + (ct * 16 + l16) * BROW;
        const int swz = l16 << 4;
#pragma unroll
        for (int rt = 0; rt < 4; ++rt) {   // rt = row group in tiled hbuf (p=0)
            const char* hsrc = hb + (rt << 16) + (lane << 4);
            f16x8 av[16];
#pragma unroll
            for (int kk = 0; kk < 16; ++kk)
                av[kk] = *(const f16x8*)(hsrc + ((wv * 16 + kk) << 10));
            f16x8 ax;
            if (wv < 3) ax = *(const f16x8*)(&xlds[rt * 16 + l16][wv * 32 + lq * 8]);
#pragma unroll
            for (int kk = 0; kk < 16; ++kk) {
                const int k0 = wv * 512 + kk * 32 + lq * 8;
                acc[rt] = mfma16(av[kk], *(const f16x8*)(brow + ((2 * k0) ^ swz)), acc[rt]);
            }
            if (wv < 3) {
                const int k0 = 2048 + wv * 32 + lq * 8;
                acc[rt] = mfma16(ax, *(const f16x8*)(brow + ((2 * k0) ^ swz)), acc[rt]);
            }
        }
        if (wv == 0) {
#pragma unroll
            for (int rt = 0; rt < 4; ++rt) *(f32x4*)(&red[rt][lane][0]) = acc[rt];
        }
        __syncthreads();
#pragma unroll
        for (int w = 1; w < 4; ++w) {
            if (wv == w) {
#pragma unroll
                for (int rt = 0; rt < 4; ++rt) {
                    f32x4 cur = *(f32x4*)(&red[rt][lane][0]);
                    cur += acc[rt];
                    *(f32x4*)(&red[rt][lane][0]) = cur;
                }
            }
            __syncthreads();
        }
        {
            const int r = tid >> 2;
            float rsum = 0.f;
#pragma unroll
            for (int q = 0; q < 4; ++q) {
                const int cl = (tid & 3) * 4 + q;
                const int c  = ct * 16 + cl;
                const int lidx = (((r & 15) >> 2) << 4) + cl;
                float v = red[r >> 4][lidx][r & 3] + b5[c0 + c];
                v = tanhf(v);
                rsum += v * Wout[c0 + c];
            }
            rowacc[r][tid & 3] += rsum;
        }
        __syncthreads();
    }
    if (tid < 64) {
        const float s = rowacc[tid][0] + rowacc[tid][1] + rowacc[tid][2] + rowacc[tid][3];
        atomicAdd(&out_pre[tid], s);
    }
}

__global__ void final_out(const float* __restrict__ out_pre,
                          const float* __restrict__ bout, float* __restrict__ out)
{
    const int b = threadIdx.x;
    if (b < BATCHN) out[b] = 1.f / (1.f + expf(-(out_pre[b] + bout[0])));
}

// ---------------------------------------------------------------------------
extern "C" void kernel_launch(void* const* d_in, const int* in_sizes, int n_in,
                              void* d_out, int out_size, void* d_ws, size_t ws_size,
                              hipStream_t stream) {
    (void)in_sizes; (void)n_in; (void)out_size; (void)ws_size;
    const int*   inputs = (const int*)d_in[0];
    const float* emb    = (const float*)d_in[1];
    const float* Wx     = (const float*)d_in[2];
    const float* Wh     = (const float*)d_in[3];
    const float* bias   = (const float*)d_in[4];
    const float* Wout   = (const float*)d_in[5];
    const float* bout   = (const float*)d_in[6];
    float* out = (float*)d_out;

    f16*   hbuf    = (f16*)d_ws;
    int*   flags   = (int*)((char*)d_ws + FLAGS_OFF);
    float* out_pre = (float*)((char*)d_ws + OUTPRE_OFF);

    // epoch-aware init (replay-deterministic):
    //   parity 0 -> 0x00 : h_0 = +0.0 with valid epoch-0 LSBs
    //   parity 1 -> 0x01 : poisoned (LSB=1 = "not yet written for epoch 0")
    //   tail     -> 0x00 : legacy flags + out_pre accumulators
    (void)hipMemsetAsync(d_ws, 0x00, PAR_BYTES, stream);
    (void)hipMemsetAsync((char*)d_ws + PAR_BYTES, 0x01, PAR_BYTES, stream);
    (void)hipMemsetAsync((char*)d_ws + HBUF_BYTES, 0x00, WS_ZERO_B - HBUF_BYTES, stream);

    hipStreamCaptureStatus cs = hipStreamCaptureStatusNone;
    (void)hipStreamIsCapturing(stream, &cs);
    if (cs == hipStreamCaptureStatusActive) {
        rnn_recur<<<dim3(128), dim3(256), 0, stream>>>(inputs, emb, Wx, Wh, bias, hbuf, flags);
    } else {
        void* args[] = {(void*)&inputs, (void*)&emb, (void*)&Wx, (void*)&Wh,
                        (void*)&bias, (void*)&hbuf, (void*)&flags};
        hipError_t e = hipLaunchCooperativeKernel((const void*)rnn_recur, dim3(128), dim3(256),
                                                  args, 0, stream);
        if (e != hipSuccess) {
            rnn_recur<<<dim3(128), dim3(256), 0, stream>>>(inputs, emb, Wx, Wh, bias, hbuf, flags);
        }
    }
    final_gemm<<<dim3(64), dim3(256), 0, stream>>>(inputs, emb, Wx, Wh, bias, Wout, hbuf, out_pre);
    final_out<<<dim3(1), dim3(64), 0, stream>>>(out_pre, bout, out);
}

// Round 10
// 359.379 us; speedup vs baseline: 2219.5237x; 1.1902x over previous
//
#include <hip/hip_runtime.h>
#include <math.h>

// Problem constants (from reference)
#define VOCABN 8192
#define EMBN   80
#define UNITSN 2048
#define BATCHN 64
#define SEQN   64
#define RBUF   4    // rotating h buffers; slot(t) = t & 3, epoch(t) = (t>>2)&3

typedef _Float16 f16;
typedef _Float16 f16x8 __attribute__((ext_vector_type(8)));
typedef float    f32x4 __attribute__((ext_vector_type(4)));
typedef unsigned int u32x4 __attribute__((ext_vector_type(4)));

// LDS geometry: B-operand slice [32 uu][2176 k] f16, XOR-swizzled rows.
#define BROW 4352

// ws layout:
//   [0, 1 MiB)   : hbuf, RBUF x [64][2048] f16. Every f16 LSB carries one bit
//                  of the 2-bit generation epoch (bit0 in even col, bit1 in
//                  odd col of each dword). Poison 0xFF = epoch 3 + garbage.
//   [1 MiB, +256): out_pre accumulators
#define HBUF_BYTES   (RBUF * BATCHN * UNITSN * 2)
#define OUTPRE_OFF   HBUF_BYTES
#define WS_ZERO_B    (OUTPRE_OFF + BATCHN * 4)

__device__ __forceinline__ f32x4 mfma16(f16x8 a, f16x8 b, f32x4 c) {
    return __builtin_amdgcn_mfma_f32_16x16x32_f16(a, b, c, 0, 0, 0);
}

// h loads: round 0 plain (L2-shared among same-XCD group members), retries
// sc0 sc1 (bypass L1+L2 -> MALL, where sc0sc1 stores are guaranteed visible).
__device__ __forceinline__ void plain_load_b16(f16x8* dst, const void* p) {
    asm volatile("global_load_dwordx4 %0, %1, off"
                 : "=v"(*dst) : "v"(p) : "memory");
}
__device__ __forceinline__ void bypass_load_b16(f16x8* dst, const void* p) {
    asm volatile("global_load_dwordx4 %0, %1, off sc0 sc1"
                 : "=v"(*dst) : "v"(p) : "memory");
}
__device__ __forceinline__ void bypass_store_b32(void* p, unsigned int v) {
    asm volatile("global_store_dword %0, %1, off sc0 sc1"
                 :: "v"(p), "v"(v) : "memory");
}
__device__ __forceinline__ void wait_vm0(void) {
    asm volatile("s_waitcnt vmcnt(0)" ::: "memory");
    __builtin_amdgcn_sched_barrier(0);
}
__device__ __forceinline__ unsigned int us(f16 h) {
    return (unsigned int)__builtin_bit_cast(unsigned short, h);
}

// Load cols [c0,c0+32) of W [2048 x 2048] (+ Wxp [80 x 2048] at k=2048..2143,
// zero-padded to 2144) as f16 into swizzled LDS: byte = uu*BROW + ((2k)^((uu&15)<<4)).
__device__ __forceinline__ void load_wslice(const float* __restrict__ W,
                                            const float* __restrict__ Wxp,
                                            int c0, int tid, unsigned char* Blds)
{
    const int j0 = tid >> 3, l8 = tid & 7;
    for (int it = 0; it < 64; ++it) {
        const int j = j0 + it * 32;
        const float4 w = *(const float4*)(W + (size_t)j * UNITSN + c0 + l8 * 4);
        const float vals[4] = {w.x, w.y, w.z, w.w};
#pragma unroll
        for (int q = 0; q < 4; ++q) {
            const int uu = l8 * 4 + q;
            *(f16*)(Blds + uu * BROW + ((2 * j) ^ ((uu & 15) << 4))) = (f16)vals[q];
        }
    }
    for (int j2 = j0; j2 < 96; j2 += 32) {
        float vals[4] = {0.f, 0.f, 0.f, 0.f};
        if (j2 < EMBN) {
            const float4 w = *(const float4*)(Wxp + (size_t)j2 * UNITSN + c0 + l8 * 4);
            vals[0] = w.x; vals[1] = w.y; vals[2] = w.z; vals[3] = w.w;
        }
#pragma unroll
        for (int q = 0; q < 4; ++q) {
            const int uu = l8 * 4 + q;
            const int k = 2048 + j2;
            *(f16*)(Blds + uu * BROW + ((2 * k) ^ ((uu & 15) << 4))) = (f16)vals[q];
        }
    }
}

// ---------------------------------------------------------------------------
// Recurrent kernel v10: round-4 geometry (4 row-groups x 64 col-chunks, LDS
// weights) + flag-free epoch-LSB dataflow over 4 rotating buffers.
// Per step: validate-poll own h fragments -> MFMA -> LDS reduce -> tanh ->
// epoch-packed sc0sc1 store (fire-and-forget). No drains, no flags, no fences.
// t=0 skips the h-part entirely (h0 = 0), so the initial slot is never read.
// ---------------------------------------------------------------------------
__global__ __launch_bounds__(256)
void rnn_recur(const int* __restrict__ inputs, const float* __restrict__ emb,
               const float* __restrict__ Wx, const float* __restrict__ Wh,
               const float* __restrict__ bias, f16* __restrict__ hbuf)
{
    __shared__ unsigned char Blds[32 * BROW];   // 139264 B
    __shared__ f16  xlds[2][16][96];            // 6144 B, double-buffered x_t
    __shared__ float red[4][2][64][4];          // 8192 B, per-wave MFMA partials
    __shared__ int  idxlds[16][SEQN];           // 4096 B, token ids

    const int tid = threadIdx.x;
    const int wg  = blockIdx.x;
    const int g     = wg >> 6;          // row group 0..3 (rows 16g..16g+15)
    const int wslot = wg & 63;          // col-chunk
    const int c0  = wslot * 32;         // output column base
    const int g16 = g * 16;

    for (int i = tid; i < 16 * SEQN; i += 256)
        idxlds[i >> 6][i & 63] = inputs[(g16 + (i >> 6)) * SEQN + (i & 63)];

    load_wslice(Wh, Wx, c0, tid, Blds);
    __syncthreads();

    // stage x_0
    {
        const int r  = tid >> 4;
        const int kb = (tid & 15) * 6;
        const float* erow = emb + (size_t)idxlds[r][0] * EMBN;
#pragma unroll
        for (int q = 0; q < 6; ++q) {
            const int k = kb + q;
            xlds[0][r][k] = (f16)((k < EMBN) ? erow[k] : 0.f);
        }
    }
    __syncthreads();

    const int lane = tid & 63;
    const int wv   = tid >> 6;      // wave 0..3: K-split
    const int l16  = lane & 15;
    const int lq   = lane >> 4;
    const int rr  = tid >> 4;       // reduce-phase output row 0..15
    const int cpa = (tid & 15) * 2; // reduce-phase output col pair
    const float ba = bias[c0 + cpa];
    const float bb = bias[c0 + cpa + 1];
    const int tla = cpa >> 4;
    const int la  = ((rr >> 2) << 4) + (cpa & 15);
    const int rg  = rr & 3;

    for (int t = 0; t < SEQN; ++t) {
        const int p = t & 1;            // xlds parity

        f32x4 acc0 = {0.f, 0.f, 0.f, 0.f};
        f32x4 acc1 = {0.f, 0.f, 0.f, 0.f};
        const int swz = l16 << 4;
        const unsigned char* brow0 = Blds + l16 * BROW;
        const unsigned char* brow1 = Blds + (16 + l16) * BROW;

        // x fragment from LDS (staged last step)
        f16x8 ax;
        if (wv < 3) ax = *(const f16x8*)(&xlds[p][l16][wv * 32 + lq * 8]);

        if (t > 0) {
            // ---- epoch-LSB validate-poll of own h_t fragments ----
            const unsigned int e  = (unsigned)(t >> 2) & 3u;
            const unsigned int eM = (e & 1u) | ((e & 2u) ? 0x00010000u : 0u);
            const f16* hrow = hbuf + (size_t)(t & 3) * BATCHN * UNITSN
                            + (size_t)(g16 + l16) * UNITSN + wv * 512 + lq * 8;
            f16x8 av[16];
            unsigned rdy = 0;
            int rounds = 0;
            for (;;) {
#pragma unroll
                for (int kk = 0; kk < 16; ++kk) {
                    if (!((rdy >> kk) & 1)) {
                        if (rounds == 0) plain_load_b16(&av[kk], hrow + kk * 32);
                        else             bypass_load_b16(&av[kk], hrow + kk * 32);
                    }
                }
                wait_vm0();
                unsigned nrdy = rdy;
#pragma unroll
                for (int kk = 0; kk < 16; ++kk) {
                    if (!((rdy >> kk) & 1)) {
                        const u32x4 d = __builtin_bit_cast(u32x4, av[kk]);
                        const bool ok = ((d[0] & 0x00010001u) == eM)
                                     && ((d[1] & 0x00010001u) == eM)
                                     && ((d[2] & 0x00010001u) == eM)
                                     && ((d[3] & 0x00010001u) == eM);
                        if (__all(ok)) nrdy |= (1u << kk);
                    }
                }
                rdy = nrdy;
                if (rdy == 0xFFFFu) break;
                if (++rounds > 20000) break;   // insurance only
                __builtin_amdgcn_s_sleep(1);
            }
            // ---- h-part MFMAs ----
#pragma unroll
            for (int kk = 0; kk < 16; ++kk) {
                const int k0 = wv * 512 + kk * 32 + lq * 8;
                const int bo = (2 * k0) ^ swz;
                acc0 = mfma16(av[kk], *(const f16x8*)(brow0 + bo), acc0);
                acc1 = mfma16(av[kk], *(const f16x8*)(brow1 + bo), acc1);
            }
        }
        // ---- x-part MFMAs (h0 = 0, so t=0 is x-only) ----
        if (wv < 3) {
            const int k0 = 2048 + wv * 32 + lq * 8;
            const int bo = (2 * k0) ^ swz;
            acc0 = mfma16(ax, *(const f16x8*)(brow0 + bo), acc0);
            acc1 = mfma16(ax, *(const f16x8*)(brow1 + bo), acc1);
        }

        *(f32x4*)(&red[wv][0][lane][0]) = acc0;
        *(f32x4*)(&red[wv][1][lane][0]) = acc1;
        __syncthreads();

        // ---- reduce 4 waves, bias, tanh, epoch-packed fire-and-forget store
        {
            float va = ba, vb = bb;
#pragma unroll
            for (int w = 0; w < 4; ++w) {
                va += red[w][tla][la][rg];
                vb += red[w][tla][la + 1][rg];
            }
            const f16 ha  = (f16)tanhf(va);
            const f16 hbv = (f16)tanhf(vb);
            const unsigned int ep = (unsigned)((t + 1) >> 2) & 3u;
            const unsigned int pk = ((us(ha)  & 0xFFFEu) | (ep & 1u))
                                  | (((us(hbv) & 0xFFFEu) | ((ep >> 1) & 1u)) << 16);
            unsigned int* dst = (unsigned int*)(hbuf
                                + (size_t)((t + 1) & 3) * BATCHN * UNITSN
                                + (size_t)(g16 + rr) * UNITSN + c0 + cpa);
            bypass_store_b32(dst, pk);   // LSB epochs ARE the ready flag
        }

        // stage x_{t+1} while stores fly
        if (t < SEQN - 1) {
            const int r  = tid >> 4;
            const int kb = (tid & 15) * 6;
            const float* erow = emb + (size_t)idxlds[r][t + 1] * EMBN;
            const int buf = (t + 1) & 1;
#pragma unroll
            for (int q = 0; q < 6; ++q) {
                const int k = kb + q;
                xlds[buf][r][k] = (f16)((k < EMBN) ? erow[k] : 0.f);
            }
        }
        __syncthreads();   // red reuse + xlds[t+1] ready
    }
}

// ---------------------------------------------------------------------------
// Final layer-5 at t=63 via MFMA (round-4 version, proven). h_64 is in slot 0
// (64 & 3 == 0) at the buffer base; LSB epochs perturb h by <=1 ulp.
// ---------------------------------------------------------------------------
__global__ __launch_bounds__(256)
void final_gemm(const int* __restrict__ inputs, const float* __restrict__ emb,
                const float* __restrict__ Wx, const float* __restrict__ Wh,
                const float* __restrict__ bias, const float* __restrict__ Wout,
                const f16* __restrict__ hbuf, float* __restrict__ out_pre)
{
    __shared__ unsigned char Blds[32 * BROW];   // 139264 B
    __shared__ f16  xlds[64][96];               // 12288 B
    __shared__ float red[4][64][4];             // 4096 B
    __shared__ float rowacc[64][4];             // 1024 B

    const int tid = threadIdx.x;
    const int c0  = blockIdx.x * 32;
    const float* Wh5 = Wh + (size_t)5 * UNITSN * UNITSN;
    const float* Wx5 = Wx + (size_t)5 * EMBN * UNITSN;
    const float* b5  = bias + 5 * UNITSN;

    load_wslice(Wh5, Wx5, c0, tid, Blds);
    {
        const int r  = tid >> 2;
        const int kb = (tid & 3) * 24;
        const float* erow = emb + (size_t)inputs[r * SEQN + SEQN - 1] * EMBN;
#pragma unroll
        for (int q = 0; q < 24; ++q) {
            const int k = kb + q;
            xlds[r][k] = (f16)((k < EMBN) ? erow[k] : 0.f);
        }
    }
    rowacc[tid >> 2][tid & 3] = 0.f;
    __syncthreads();

    const int lane = tid & 63;
    const int wv   = tid >> 6;
    const int l16  = lane & 15;
    const int lq   = lane >> 4;

    for (int ct = 0; ct < 2; ++ct) {
        f32x4 acc[4];
#pragma unroll
        for (int rt = 0; rt < 4; ++rt) acc[rt] = (f32x4){0.f, 0.f, 0.f, 0.f};
        const unsigned char* brow = Blds + (ct * 16 + l16) * BROW;
        const int swz = l16 << 4;
#pragma unroll
        for (int rt = 0; rt < 4; ++rt) {
            const f16* hrow = hbuf + (size_t)(rt * 16 + l16) * UNITSN + wv * 512 + lq * 8;
            f16x8 av[16];
#pragma unroll
            for (int kk = 0; kk < 16; ++kk)
                av[kk] = *(const f16x8*)(hrow + kk * 32);
            f16x8 ax;
            if (wv < 3) ax = *(const f16x8*)(&xlds[rt * 16 + l16][wv * 32 + lq * 8]);
#pragma unroll
            for (int kk = 0; kk < 16; ++kk) {
                const int k0 = wv * 512 + kk * 32 + lq * 8;
                acc[rt] = mfma16(av[kk], *(const f16x8*)(brow + ((2 * k0) ^ swz)), acc[rt]);
            }
            if (wv < 3) {
                const int k0 = 2048 + wv * 32 + lq * 8;
                acc[rt] = mfma16(ax, *(const f16x8*)(brow + ((2 * k0) ^ swz)), acc[rt]);
            }
        }
        if (wv == 0) {
#pragma unroll
            for (int rt = 0; rt < 4; ++rt) *(f32x4*)(&red[rt][lane][0]) = acc[rt];
        }
        __syncthreads();
#pragma unroll
        for (int w = 1; w < 4; ++w) {
            if (wv == w) {
#pragma unroll
                for (int rt = 0; rt < 4; ++rt) {
                    f32x4 cur = *(f32x4*)(&red[rt][lane][0]);
                    cur += acc[rt];
                    *(f32x4*)(&red[rt][lane][0]) = cur;
                }
            }
            __syncthreads();
        }
        {
            const int r = tid >> 2;
            float rsum = 0.f;
#pragma unroll
            for (int q = 0; q < 4; ++q) {
                const int cl = (tid & 3) * 4 + q;
                const int c  = ct * 16 + cl;
                const int lidx = (((r & 15) >> 2) << 4) + cl;
                float v = red[r >> 4][lidx][r & 3] + b5[c0 + c];
                v = tanhf(v);
                rsum += v * Wout[c0 + c];
            }
            rowacc[r][tid & 3] += rsum;
        }
        __syncthreads();
    }
    if (tid < 64) {
        const float s = rowacc[tid][0] + rowacc[tid][1] + rowacc[tid][2] + rowacc[tid][3];
        atomicAdd(&out_pre[tid], s);
    }
}

__global__ void final_out(const float* __restrict__ out_pre,
                          const float* __restrict__ bout, float* __restrict__ out)
{
    const int b = threadIdx.x;
    if (b < BATCHN) out[b] = 1.f / (1.f + expf(-(out_pre[b] + bout[0])));
}

// ---------------------------------------------------------------------------
extern "C" void kernel_launch(void* const* d_in, const int* in_sizes, int n_in,
                              void* d_out, int out_size, void* d_ws, size_t ws_size,
                              hipStream_t stream) {
    (void)in_sizes; (void)n_in; (void)out_size; (void)ws_size;
    const int*   inputs = (const int*)d_in[0];
    const float* emb    = (const float*)d_in[1];
    const float* Wx     = (const float*)d_in[2];
    const float* Wh     = (const float*)d_in[3];
    const float* bias   = (const float*)d_in[4];
    const float* Wout   = (const float*)d_in[5];
    const float* bout   = (const float*)d_in[6];
    float* out = (float*)d_out;

    f16*   hbuf    = (f16*)d_ws;
    float* out_pre = (float*)((char*)d_ws + OUTPRE_OFF);

    // 0xFF poison = epoch 3 (never expected) in every dword; slot for h_0 is
    // never read (t=0 skips the h-part since h_0 = 0). Replay-deterministic.
    (void)hipMemsetAsync(d_ws, 0xFF, HBUF_BYTES, stream);
    (void)hipMemsetAsync((char*)d_ws + OUTPRE_OFF, 0x00, WS_ZERO_B - OUTPRE_OFF, stream);

    hipStreamCaptureStatus cs = hipStreamCaptureStatusNone;
    (void)hipStreamIsCapturing(stream, &cs);
    if (cs == hipStreamCaptureStatusActive) {
        rnn_recur<<<dim3(256), dim3(256), 0, stream>>>(inputs, emb, Wx, Wh, bias, hbuf);
    } else {
        void* args[] = {(void*)&inputs, (void*)&emb, (void*)&Wx, (void*)&Wh,
                        (void*)&bias, (void*)&hbuf};
        hipError_t e = hipLaunchCooperativeKernel((const void*)rnn_recur, dim3(256), dim3(256),
                                                  args, 0, stream);
        if (e != hipSuccess) {
            rnn_recur<<<dim3(256), dim3(256), 0, stream>>>(inputs, emb, Wx, Wh, bias, hbuf);
        }
    }
    final_gemm<<<dim3(64), dim3(256), 0, stream>>>(inputs, emb, Wx, Wh, bias, Wout, hbuf, out_pre);
    final_out<<<dim3(1), dim3(64), 0, stream>>>(out_pre, bout, out);
}